// Round 1
// 129.880 us; speedup vs baseline: 1.0652x; 1.0652x over previous
//
#include <hip/hip_runtime.h>
#include <math.h>

#define ALPHA_C (-0.01f)
#define BLOCK 256
#define WPW 11              // windows resolved per wave
#define SPAN_F 3072         // floats staged per wave (12 KB); windows need 3000+neighbor
#define ROUNDS 12           // 12 x (64 lanes x 16 B) = 12 KB async stages

typedef __attribute__((address_space(3))) unsigned char* lds_ptr_t;
typedef const __attribute__((address_space(1))) unsigned char* gbl_ptr_t;

__global__ __launch_bounds__(BLOCK, 3)
void softmin_dtw_kernel(const float* __restrict__ x, const float* __restrict__ S,
                        float* __restrict__ out, long long Q, int W,
                        float inv_W) {
  __shared__ __align__(16) float sX[4][SPAN_F];   // per-wave private spans
  __shared__ __align__(16) float sS[512];         // shared S copy (2 KB)
  __shared__ float sRed[4];

  const int tid  = threadIdx.x;
  const int wid  = tid >> 6;
  const int lane = tid & 63;

  const long long gw = 4LL * blockIdx.x + wid;    // global wave id
  const long long w0 = gw * WPW;                  // first window of this wave
  const long long b0 = w0 * 250LL;                // first float of the span
  const bool wave_active = (w0 < (long long)W);

  // ---- per-wave async staging: direct global->LDS, issued back-to-back ----
  if (wave_active) {
    #pragma unroll
    for (int r = 0; r < ROUNDS; ++r) {
      const long long gp = b0 + 256LL * r + 4LL * lane;   // float index
      if (b0 + 256LL * (r + 1) <= Q) {
        // dest = wave-uniform base + lane*16B (linear), src per-lane
        __builtin_amdgcn_global_load_lds(
            (gbl_ptr_t)(const void*)(x + gp),
            (lds_ptr_t)(void*)(&sX[wid][256 * r]),
            16, 0, 0);
      } else {
        // tail (last wave only): guarded scalar path
        float4 v;
        v.x = (gp     < Q) ? x[gp]     : 0.f;
        v.y = (gp + 1 < Q) ? x[gp + 1] : 0.f;
        v.z = (gp + 2 < Q) ? x[gp + 2] : 0.f;
        v.w = (gp + 3 < Q) ? x[gp + 3] : 0.f;
        *reinterpret_cast<float4*>(&sX[wid][256 * r + 4 * lane]) = v;
      }
    }
  }

  // ---- shared S copy (2 KB) ----
  if (tid < 125)
    *reinterpret_cast<float4*>(&sS[tid * 4]) =
        *reinterpret_cast<const float4*>(&S[tid * 4]);

  // ---- yy[j]: lanes 0..4 of every wave, straight from global S (L2-hot);
  //      overlaps the staging latency, no LDS ordering dependence ----
  float yyv = 0.f;
  if (lane < 5) {
    const float* sp = S + 100 * lane;
    #pragma unroll
    for (int s = 0; s < 100; s += 4) {
      const float4 v = *reinterpret_cast<const float4*>(&sp[s]);
      yyv = fmaf(v.x, v.x, fmaf(v.y, v.y, fmaf(v.z, v.z, fmaf(v.w, v.w, yyv))));
    }
  }

  __syncthreads();  // drains this wave's global_load_lds (vmcnt) + sS visible

  const float yy0 = __shfl(yyv, 0);
  const float yy1 = __shfl(yyv, 1);
  const float yy2 = __shfl(yyv, 2);
  const float yy3 = __shfl(yyv, 3);
  const float yy4 = __shfl(yyv, 4);

  // ---- per-chunk partial dots (chunk = lane; lanes >=60 duplicate chunk 59) ----
  const int cc = (lane < 60) ? lane : 59;
  const int i0 = (3 * cc) % 5;        // even-position segment row
  const int i1 = (i0 + 2) % 5;        // odd-position segment row
  const int a0 = (i0 > 0 ? i0 - 1 : 0) * 100;
  const int a1 = i0 * 100;
  const int a2 = (i0 < 4 ? i0 + 1 : 4) * 100;
  const int e0 = (i1 > 0 ? i1 - 1 : 0) * 100 + 50;
  const int e1 = i1 * 100 + 50;
  const int e2 = (i1 < 4 ? i1 + 1 : 4) * 100 + 50;

  float sq = 0.f, A0 = 0.f, A1 = 0.f, A2 = 0.f, B0 = 0.f, B1 = 0.f, B2 = 0.f;
  const float* xc = &sX[wid][cc * 50];
  #pragma unroll 5
  for (int t = 0; t < 50; t += 2) {
    const float2 xv = *reinterpret_cast<const float2*>(&xc[t]);
    float2 y;
    sq = fmaf(xv.x, xv.x, fmaf(xv.y, xv.y, sq));
    y = *reinterpret_cast<const float2*>(&sS[a0 + t]);
    A0 = fmaf(xv.x, y.x, fmaf(xv.y, y.y, A0));
    y = *reinterpret_cast<const float2*>(&sS[a1 + t]);
    A1 = fmaf(xv.x, y.x, fmaf(xv.y, y.y, A1));
    y = *reinterpret_cast<const float2*>(&sS[a2 + t]);
    A2 = fmaf(xv.x, y.x, fmaf(xv.y, y.y, A2));
    y = *reinterpret_cast<const float2*>(&sS[e0 + t]);
    B0 = fmaf(xv.x, y.x, fmaf(xv.y, y.y, B0));
    y = *reinterpret_cast<const float2*>(&sS[e1 + t]);
    B1 = fmaf(xv.x, y.x, fmaf(xv.y, y.y, B1));
    y = *reinterpret_cast<const float2*>(&sS[e2 + t]);
    B2 = fmaf(xv.x, y.x, fmaf(xv.y, y.y, B2));
  }

  // ---- neighbor combine via shfl (odd chunk c+1 supplies sq/B*) ----
  const float nsq = __shfl_down(sq, 1);
  const float nB0 = __shfl_down(B0, 1);
  const float nB1 = __shfl_down(B1, 1);
  const float nB2 = __shfl_down(B2, 1);

  const float cell_xx = sq + nsq;   // xx of segment row i0 (both halves)
  const float cell_p  = A0 + nB0;   // xy(i0, i0-1)
  const float cell_m  = A1 + nB1;   // xy(i0, i0)
  const float cell_n  = A2 + nB2;   // xy(i0, i0+1)

  // ---- gather band rows to window-owner lane lw via bpermute ----
  float r_xx[5], r_p[5], r_m[5], r_n[5];
  #pragma unroll
  for (int i = 0; i < 5; ++i) {
    const int src = 5 * lane + 2 * i;   // <=58 for lane<11; garbage otherwise
    r_xx[i] = __shfl(cell_xx, src);
    r_p[i]  = __shfl(cell_p, src);
    r_m[i]  = __shfl(cell_m, src);
    r_n[i]  = __shfl(cell_n, src);
  }

  // ---- banded DTW + exp, one window per lane (lanes 0..10) ----
  float xi = 0.f;
  if (lane < WPW && w0 + lane < (long long)W) {
    const float C00 = r_xx[0] + yy0 - 2.f * r_m[0];
    const float C01 = r_xx[0] + yy1 - 2.f * r_n[0];
    const float C10 = r_xx[1] + yy0 - 2.f * r_p[1];
    const float C11 = r_xx[1] + yy1 - 2.f * r_m[1];
    const float C12 = r_xx[1] + yy2 - 2.f * r_n[1];
    const float C21 = r_xx[2] + yy1 - 2.f * r_p[2];
    const float C22 = r_xx[2] + yy2 - 2.f * r_m[2];
    const float C23 = r_xx[2] + yy3 - 2.f * r_n[2];
    const float C32 = r_xx[3] + yy2 - 2.f * r_p[3];
    const float C33 = r_xx[3] + yy3 - 2.f * r_m[3];
    const float C34 = r_xx[3] + yy4 - 2.f * r_n[3];
    const float C43 = r_xx[4] + yy3 - 2.f * r_p[4];
    const float C44 = r_xx[4] + yy4 - 2.f * r_m[4];

    const float c11v = C00;
    const float c12v = C01 + c11v;
    const float c21v = C10 + c11v;
    const float c22v = C11 + fminf(fminf(c12v, c21v), c11v);
    const float c23v = C12 + fminf(c22v, c12v);
    const float c32v = C21 + fminf(c22v, c21v);
    const float c33v = C22 + fminf(fminf(c23v, c32v), c22v);
    const float c34v = C23 + fminf(c33v, c23v);
    const float c43v = C32 + fminf(c33v, c32v);
    const float c44v = C33 + fminf(fminf(c34v, c43v), c33v);
    const float c45v = C34 + fminf(c44v, c34v);
    const float c54v = C43 + fminf(c44v, c43v);
    const float c55v = C44 + fminf(fminf(c45v, c54v), c44v);

    xi = expf(ALPHA_C * sqrtf(fmaxf(c55v, 0.f)));
  }

  // ---- wave reduce (lanes >10 hold 0), then tiny block reduce, one atomic ----
  #pragma unroll
  for (int off = 32; off > 0; off >>= 1) xi += __shfl_down(xi, off);
  if (lane == 0) sRed[wid] = xi;
  __syncthreads();
  if (tid == 0)
    atomicAdd(out, (sRed[0] + sRed[1] + sRed[2] + sRed[3]) * inv_W);
}

extern "C" void kernel_launch(void* const* d_in, const int* in_sizes, int n_in,
                              void* d_out, int out_size, void* d_ws, size_t ws_size,
                              hipStream_t stream) {
  const float* x = (const float*)d_in[0];
  const float* S = (const float*)d_in[1];
  float* out = (float*)d_out;

  const long long Q = in_sizes[0];
  const int L = in_sizes[1];   // 500
  const int step = L / 2;      // 250
  const long long n = Q - L;
  const int W = (int)((n + step - 1) / step);  // 79998

  hipMemsetAsync(out, 0, sizeof(float), stream);

  const int waves = (W + WPW - 1) / WPW;       // 7273
  const int blocks = (waves + 3) / 4;          // 1819
  softmin_dtw_kernel<<<blocks, BLOCK, 0, stream>>>(x, S, out, Q, W,
                                                   1.0f / (float)W);
}

// Round 2
// 119.031 us; speedup vs baseline: 1.1623x; 1.0911x over previous
//
#include <hip/hip_runtime.h>
#include <math.h>

#define ALPHA_C (-0.01f)
#define BLOCK 256
#define WPW 11              // windows resolved per wave
#define SPAN_F 3072         // floats staged per wave (12 KB)
#define ROUNDS 12           // 12 x (64 lanes x 16 B) = 12 KB async stages

typedef __attribute__((address_space(3))) unsigned char* lds_ptr_t;
typedef const __attribute__((address_space(1))) unsigned char* gbl_ptr_t;

__global__ __launch_bounds__(BLOCK, 3)
void softmin_dtw_kernel(const float* __restrict__ x, const float* __restrict__ S,
                        float* __restrict__ partials, long long Q, int W) {
  __shared__ __align__(16) float sX[4][SPAN_F];   // per-wave private spans
  __shared__ __align__(16) float sS[512];         // shared S copy (2 KB)
  __shared__ float sRed[4];

  const int tid  = threadIdx.x;
  const int wid  = tid >> 6;
  const int lane = tid & 63;

  const long long gw = 4LL * blockIdx.x + wid;    // global wave id
  const long long w0 = gw * WPW;                  // first window of this wave
  const long long b0 = w0 * 250LL;                // first float of the span
  const bool wave_active = (w0 < (long long)W);

  // ---- per-wave async staging: direct global->LDS, issued back-to-back ----
  if (wave_active) {
    #pragma unroll
    for (int r = 0; r < ROUNDS; ++r) {
      const long long gp = b0 + 256LL * r + 4LL * lane;   // float index
      if (b0 + 256LL * (r + 1) <= Q) {
        __builtin_amdgcn_global_load_lds(
            (gbl_ptr_t)(const void*)(x + gp),
            (lds_ptr_t)(void*)(&sX[wid][256 * r]),
            16, 0, 0);
      } else {
        float4 v;
        v.x = (gp     < Q) ? x[gp]     : 0.f;
        v.y = (gp + 1 < Q) ? x[gp + 1] : 0.f;
        v.z = (gp + 2 < Q) ? x[gp + 2] : 0.f;
        v.w = (gp + 3 < Q) ? x[gp + 3] : 0.f;
        *reinterpret_cast<float4*>(&sX[wid][256 * r + 4 * lane]) = v;
      }
    }
  }

  // ---- shared S copy (2 KB) ----
  if (tid < 125)
    *reinterpret_cast<float4*>(&sS[tid * 4]) =
        *reinterpret_cast<const float4*>(&S[tid * 4]);

  // ---- yy[j]: lanes 0..4, straight from global S (L2-hot), overlaps staging ----
  float yyv = 0.f;
  if (lane < 5) {
    const float* sp = S + 100 * lane;
    #pragma unroll
    for (int s = 0; s < 100; s += 4) {
      const float4 v = *reinterpret_cast<const float4*>(&sp[s]);
      yyv = fmaf(v.x, v.x, fmaf(v.y, v.y, fmaf(v.z, v.z, fmaf(v.w, v.w, yyv))));
    }
  }

  __syncthreads();  // drains global_load_lds (vmcnt) + sS visible

  const float yy0 = __shfl(yyv, 0);
  const float yy1 = __shfl(yyv, 1);
  const float yy2 = __shfl(yyv, 2);
  const float yy3 = __shfl(yyv, 3);
  const float yy4 = __shfl(yyv, 4);

  // ---- per-chunk partial dots (chunk = lane; lanes >=60 duplicate chunk 59) ----
  const int cc = (lane < 60) ? lane : 59;
  const int i0 = (3 * cc) % 5;        // even-position segment row
  const int i1 = (i0 + 2) % 5;        // odd-position segment row
  const int a0 = (i0 > 0 ? i0 - 1 : 0) * 100;
  const int a1 = i0 * 100;
  const int a2 = (i0 < 4 ? i0 + 1 : 4) * 100;
  const int e0 = (i1 > 0 ? i1 - 1 : 0) * 100 + 50;
  const int e1 = i1 * 100 + 50;
  const int e2 = (i1 < 4 ? i1 + 1 : 4) * 100 + 50;

  float sq = 0.f, A0 = 0.f, A1 = 0.f, A2 = 0.f, B0 = 0.f, B1 = 0.f, B2 = 0.f;
  const float* xc = &sX[wid][cc * 50];
  #pragma unroll 5
  for (int t = 0; t < 50; t += 2) {
    const float2 xv = *reinterpret_cast<const float2*>(&xc[t]);
    float2 y;
    sq = fmaf(xv.x, xv.x, fmaf(xv.y, xv.y, sq));
    y = *reinterpret_cast<const float2*>(&sS[a0 + t]);
    A0 = fmaf(xv.x, y.x, fmaf(xv.y, y.y, A0));
    y = *reinterpret_cast<const float2*>(&sS[a1 + t]);
    A1 = fmaf(xv.x, y.x, fmaf(xv.y, y.y, A1));
    y = *reinterpret_cast<const float2*>(&sS[a2 + t]);
    A2 = fmaf(xv.x, y.x, fmaf(xv.y, y.y, A2));
    y = *reinterpret_cast<const float2*>(&sS[e0 + t]);
    B0 = fmaf(xv.x, y.x, fmaf(xv.y, y.y, B0));
    y = *reinterpret_cast<const float2*>(&sS[e1 + t]);
    B1 = fmaf(xv.x, y.x, fmaf(xv.y, y.y, B1));
    y = *reinterpret_cast<const float2*>(&sS[e2 + t]);
    B2 = fmaf(xv.x, y.x, fmaf(xv.y, y.y, B2));
  }

  // ---- neighbor combine via shfl (odd chunk c+1 supplies sq/B*) ----
  const float nsq = __shfl_down(sq, 1);
  const float nB0 = __shfl_down(B0, 1);
  const float nB1 = __shfl_down(B1, 1);
  const float nB2 = __shfl_down(B2, 1);

  const float cell_xx = sq + nsq;   // xx of segment row i0 (both halves)
  const float cell_p  = A0 + nB0;   // xy(i0, i0-1)
  const float cell_m  = A1 + nB1;   // xy(i0, i0)
  const float cell_n  = A2 + nB2;   // xy(i0, i0+1)

  // ---- gather band rows to window-owner lane via shfl ----
  float r_xx[5], r_p[5], r_m[5], r_n[5];
  #pragma unroll
  for (int i = 0; i < 5; ++i) {
    const int src = 5 * lane + 2 * i;   // <=58 for lane<11; garbage otherwise
    r_xx[i] = __shfl(cell_xx, src);
    r_p[i]  = __shfl(cell_p, src);
    r_m[i]  = __shfl(cell_m, src);
    r_n[i]  = __shfl(cell_n, src);
  }

  // ---- banded DTW + exp, one window per lane (lanes 0..10) ----
  float xi = 0.f;
  if (lane < WPW && w0 + lane < (long long)W) {
    const float C00 = r_xx[0] + yy0 - 2.f * r_m[0];
    const float C01 = r_xx[0] + yy1 - 2.f * r_n[0];
    const float C10 = r_xx[1] + yy0 - 2.f * r_p[1];
    const float C11 = r_xx[1] + yy1 - 2.f * r_m[1];
    const float C12 = r_xx[1] + yy2 - 2.f * r_n[1];
    const float C21 = r_xx[2] + yy1 - 2.f * r_p[2];
    const float C22 = r_xx[2] + yy2 - 2.f * r_m[2];
    const float C23 = r_xx[2] + yy3 - 2.f * r_n[2];
    const float C32 = r_xx[3] + yy2 - 2.f * r_p[3];
    const float C33 = r_xx[3] + yy3 - 2.f * r_m[3];
    const float C34 = r_xx[3] + yy4 - 2.f * r_n[3];
    const float C43 = r_xx[4] + yy3 - 2.f * r_p[4];
    const float C44 = r_xx[4] + yy4 - 2.f * r_m[4];

    const float c11v = C00;
    const float c12v = C01 + c11v;
    const float c21v = C10 + c11v;
    const float c22v = C11 + fminf(fminf(c12v, c21v), c11v);
    const float c23v = C12 + fminf(c22v, c12v);
    const float c32v = C21 + fminf(c22v, c21v);
    const float c33v = C22 + fminf(fminf(c23v, c32v), c22v);
    const float c34v = C23 + fminf(c33v, c23v);
    const float c43v = C32 + fminf(c33v, c32v);
    const float c44v = C33 + fminf(fminf(c34v, c43v), c33v);
    const float c45v = C34 + fminf(c44v, c34v);
    const float c54v = C43 + fminf(c44v, c43v);
    const float c55v = C44 + fminf(fminf(c45v, c54v), c44v);

    xi = expf(ALPHA_C * sqrtf(fmaxf(c55v, 0.f)));
  }

  // ---- wave reduce, block reduce, ONE plain store per block (no atomic) ----
  #pragma unroll
  for (int off = 32; off > 0; off >>= 1) xi += __shfl_down(xi, off);
  if (lane == 0) sRed[wid] = xi;
  __syncthreads();
  if (tid == 0)
    partials[blockIdx.x] = sRed[0] + sRed[1] + sRed[2] + sRed[3];
}

__global__ __launch_bounds__(256)
void reduce_partials(const float* __restrict__ partials, float* __restrict__ out,
                     int n, float inv_W) {
  __shared__ float sR[4];
  const int tid = threadIdx.x;
  float a = 0.f;
  for (int i = tid; i < n; i += 256) a += partials[i];
  #pragma unroll
  for (int off = 32; off > 0; off >>= 1) a += __shfl_down(a, off);
  if ((tid & 63) == 0) sR[tid >> 6] = a;
  __syncthreads();
  if (tid == 0) out[0] = (sR[0] + sR[1] + sR[2] + sR[3]) * inv_W;
}

extern "C" void kernel_launch(void* const* d_in, const int* in_sizes, int n_in,
                              void* d_out, int out_size, void* d_ws, size_t ws_size,
                              hipStream_t stream) {
  const float* x = (const float*)d_in[0];
  const float* S = (const float*)d_in[1];
  float* out = (float*)d_out;
  float* partials = (float*)d_ws;

  const long long Q = in_sizes[0];
  const int L = in_sizes[1];   // 500
  const int step = L / 2;      // 250
  const long long n = Q - L;
  const int W = (int)((n + step - 1) / step);  // 79998

  const int waves = (W + WPW - 1) / WPW;       // 7273
  const int blocks = (waves + 3) / 4;          // 1819

  softmin_dtw_kernel<<<blocks, BLOCK, 0, stream>>>(x, S, partials, Q, W);
  reduce_partials<<<1, 256, 0, stream>>>(partials, out, blocks,
                                         1.0f / (float)W);
}